// Round 4
// baseline (108.901 us; speedup 1.0000x reference)
//
#include <hip/hip_runtime.h>

// NeighborList: N=4096, cutoff 5.0, all pairs i<j (P = N(N-1)/2 = 8,386,560).
// Output (floats): [0,P) pair_i | [P,2P) pair_j | [2P,5P) diff[P,3] | [5P,6P) dist | [6P] n_pairs
//
// R3: linear-p mapping (4 pairs/thread, aligned float4 stores, zero dead
// threads). Changes vs R2: (a) p->row inversion via exact-int64 radicand +
// sqrtf instead of fp64 sqrt (fixup loops absorb the +-2 error); (b) all
// output stores nontemporal (201 MB streaming, don't thrash 32MB L2).
// Count: per-block plain store to ws[bid], tiny finalize sums.

typedef float f4 __attribute__((ext_vector_type(4)));

__global__ void zero_ws(int* __restrict__ ws, int n) {
    int t = blockIdx.x * blockDim.x + threadIdx.x;
    if (t < n) ws[t] = 0;
}

__global__ __launch_bounds__(256) void nl_kernel(const float* __restrict__ xyz,
                                                 float* __restrict__ out,
                                                 int* __restrict__ ws,
                                                 int N, int P, int slots) {
    const int p0 = (blockIdx.x * 256 + threadIdx.x) * 4;
    int cnt = 0;
    if (p0 < P) {
        // invert p -> row i: rowstart(i) = i*(2N-1-i)/2 <= p.
        // radicand (2N-1)^2 - 8p fits exactly in <2^27; sqrtf gives i +- ~2,
        // integer fixup below makes it exact.
        const int twoNm1 = 2 * N - 1;
        const long long rad = (long long)twoNm1 * twoNm1 - 8LL * (long long)p0;
        const float s = sqrtf((float)rad);
        int i = (int)(((float)twoNm1 - s) * 0.5f);
        if (i > N - 2) i = N - 2;
        if (i < 0) i = 0;
        int rs = i * (2 * N - 1 - i) / 2;
        while (p0 < rs) { --i; rs -= (N - 1 - i); }          // fixup down
        int next = rs + (N - 1 - i);
        while (p0 >= next && i < N - 2) { ++i; rs = next; next += (N - 1 - i); }

        float iv[4], jv[4], dxs[4], dys[4], dzs[4], dv[4];
        #pragma unroll
        for (int e = 0; e < 4; ++e) {
            const int p = p0 + e;
            while (p >= next && i < N - 2) { ++i; rs = next; next += (N - 1 - i); }
            const int j = i + 1 + (p - rs);
            float dx = 0.f, dy = 0.f, dz = 0.f, dist = 0.f, fi = -1.f, fj = -1.f;
            if (p < P) {
                const float ax = xyz[3 * i], ay = xyz[3 * i + 1], az = xyz[3 * i + 2];
                const float bx = xyz[3 * j], by = xyz[3 * j + 1], bz = xyz[3 * j + 2];
                const float tx = ax - bx, ty = ay - by, tz = az - bz;
                const float d = sqrtf(tx * tx + ty * ty + tz * tz);
                if (d < 5.0f) {                    // mirror reference: sqrt then compare
                    fi = (float)i; fj = (float)j;
                    dx = tx; dy = ty; dz = tz; dist = d;
                    ++cnt;
                }
            }
            iv[e] = fi; jv[e] = fj; dxs[e] = dx; dys[e] = dy; dzs[e] = dz; dv[e] = dist;
        }

        if (p0 + 4 <= P) {   // p0 mult of 4 -> all 16B-aligned
            __builtin_nontemporal_store((f4){iv[0], iv[1], iv[2], iv[3]}, (f4*)(out + p0));
            __builtin_nontemporal_store((f4){jv[0], jv[1], jv[2], jv[3]}, (f4*)(out + P + p0));
            f4* dp = (f4*)(out + 2 * P + 3 * p0);
            __builtin_nontemporal_store((f4){dxs[0], dys[0], dzs[0], dxs[1]}, dp + 0);
            __builtin_nontemporal_store((f4){dys[1], dzs[1], dxs[2], dys[2]}, dp + 1);
            __builtin_nontemporal_store((f4){dzs[2], dxs[3], dys[3], dzs[3]}, dp + 2);
            __builtin_nontemporal_store((f4){dv[0], dv[1], dv[2], dv[3]}, (f4*)(out + 5 * P + p0));
        } else {
            for (int e = 0; e < 4 && p0 + e < P; ++e) {
                const int p = p0 + e;
                out[p] = iv[e]; out[P + p] = jv[e];
                out[2 * P + 3 * p]     = dxs[e];
                out[2 * P + 3 * p + 1] = dys[e];
                out[2 * P + 3 * p + 2] = dzs[e];
                out[5 * P + p] = dv[e];
            }
        }
    }

    // per-block count -> ws (plain store if ws has a slot per block, else hashed atomic)
    for (int o = 32; o > 0; o >>= 1) cnt += __shfl_down(cnt, o, 64);
    __shared__ int sh[4];
    if ((threadIdx.x & 63) == 0) sh[threadIdx.x >> 6] = cnt;
    __syncthreads();
    if (threadIdx.x == 0) {
        const int c = sh[0] + sh[1] + sh[2] + sh[3];
        if ((int)gridDim.x <= slots) ws[blockIdx.x] = c;
        else if (c) atomicAdd(&ws[blockIdx.x % slots], c);
    }
}

__global__ void finalize_kernel(float* __restrict__ out, const int* __restrict__ ws,
                                int n, int pos) {
    const int t = threadIdx.x;  // 256
    int s = 0;
    for (int k = t; k < n; k += 256) s += ws[k];
    for (int o = 32; o > 0; o >>= 1) s += __shfl_down(s, o, 64);
    __shared__ int sh[4];
    if ((t & 63) == 0) sh[t >> 6] = s;
    __syncthreads();
    if (t == 0) out[pos] = (float)(sh[0] + sh[1] + sh[2] + sh[3]);
}

extern "C" void kernel_launch(void* const* d_in, const int* in_sizes, int n_in,
                              void* d_out, int out_size, void* d_ws, size_t ws_size,
                              hipStream_t stream) {
    const float* xyz = (const float*)d_in[0];
    float* out = (float*)d_out;
    int* ws = (int*)d_ws;

    const int N = in_sizes[0] / 3;                          // 4096
    const int P = (int)((long long)N * (N - 1) / 2);        // 8,386,560

    const int nb = (P + 1023) / 1024;                       // 4 pairs/thread, 256 thr/block
    const int cap = (int)(ws_size / 4);
    const int slots = (nb <= cap) ? nb : (cap < 1 ? 1 : (cap > 1024 ? 1024 : cap));
    if (nb > slots) zero_ws<<<(slots + 255) / 256, 256, 0, stream>>>(ws, slots);

    nl_kernel<<<nb, 256, 0, stream>>>(xyz, out, ws, N, P, slots);
    finalize_kernel<<<1, 256, 0, stream>>>(out, ws, slots, 6 * P);
}